// Round 17
// baseline (293.587 us; speedup 1.0000x reference)
//
#include <hip/hip_runtime.h>
#include <math.h>

#define NB 2
#define CIN 64
#define DD_ 64
#define HH_ 64
#define WW_ 64
#define NCLS 5
#define LL (DD_*HH_*WW_)   /* 262144 */
#define NMAXG 32
#define TOPKK 13
#define NSLAB 4
#define BUFSZ 38016        /* 36 rows * 66 wp * 16 fp8 bytes */

typedef __attribute__((ext_vector_type(16))) float floatx16;

__device__ __forceinline__ float softplusf_(float z){
  return fmaxf(z, 0.f) + log1pf(expf(-fabsf(z)));
}
__device__ __forceinline__ float sigmoidf_(float z){
  return 1.f/(1.f + expf(-z));
}
// fp32 -> fp8 e4m3fn, RNE, saturate to 448
__device__ __forceinline__ unsigned tofp8_(float x){
  unsigned u = __float_as_uint(x);
  unsigned sign = (u >> 24) & 0x80u;
  unsigned a = u & 0x7FFFFFFFu;
  if (a >= 0x43E00000u) return sign | 0x7Eu;
  if (a < 0x3C800000u){
    float fa = __uint_as_float(a);
    int m = (int)rintf(fa * 512.f);
    return sign | (unsigned)m;
  }
  unsigned bb = a + 0x7FFFFu + ((a >> 20) & 1u);
  unsigned e8 = ((bb >> 23) & 0xFFu) - 120u;
  unsigned m8 = (bb >> 20) & 7u;
  if (e8 > 15u || (e8 == 15u && m8 > 6u)) return sign | 0x7Eu;
  return sign | (e8 << 3) | m8;
}

// ---------------- Phase 0: fused transpose fp32 NCDHW -> fp8 [b][cc][voxel][16c]
// + weight->fp8 A-fragment build + bg/moff/ticket zero init.
__global__ __launch_bounds__(256) void transpose_kernel(
    const float* __restrict__ feat, unsigned char* __restrict__ featT,
    const float* __restrict__ cls_w, const float* __restrict__ off_w,
    unsigned char* __restrict__ wA, float* __restrict__ bgz)
{
  const int t = threadIdx.x;
  const int w = t & 63;
  const int hh = t >> 6;                 // 0..3
  const int d = blockIdx.x;
  const int h = blockIdx.y*4 + hh;
  const int b = blockIdx.z;
  const float* src = feat + (size_t)b*CIN*LL + (size_t)d*4096 + (size_t)h*64 + w;
  const size_t sp = (size_t)d*4096 + (size_t)h*64 + w;
  #pragma unroll
  for (int cc=0; cc<4; ++cc){
    unsigned q[16];
    #pragma unroll
    for (int j=0;j<16;++j) q[j] = tofp8_(src[(size_t)(cc*16+j)*LL]);
    uint4 p;
    p.x = q[0] | (q[1]<<8) | (q[2]<<16) | (q[3]<<24);
    p.y = q[4] | (q[5]<<8) | (q[6]<<16) | (q[7]<<24);
    p.z = q[8] | (q[9]<<8) | (q[10]<<16) | (q[11]<<24);
    p.w = q[12] | (q[13]<<8) | (q[14]<<16) | (q[15]<<24);
    *(uint4*)(featT + ((size_t)(b*4+cc)*LL + sp)*16) = p;
  }
  if (blockIdx.z == 0 && blockIdx.y == 0 && blockIdx.x < 54){
    if (blockIdx.x == 0 && t < 8) bgz[t] = 0.f;   // bg, moff, pad, pad, ticket...
    int idx = blockIdx.x*256 + t;
    int slice = idx >> 6; int lane = idx & 63;
    int cc = slice & 3; int r = slice >> 2;       // r = rr*9 + kh*3 + kw
    int kw = r % 3; int r2 = r / 3;
    int kh = r2 % 3; int rr = r2 / 3;             // 0..5
    int m = lane & 31, khalf = lane >> 5;
    int outch = m & 7;
    int kd = rr - (m >> 3);
    unsigned q[8];
    #pragma unroll
    for (int i=0;i<8;++i){
      int c = cc*16 + khalf*8 + i;
      float wv = 0.f;
      if (kd >= 0 && kd <= 2){
        if (outch < NCLS) wv = cls_w[(outch*CIN + c)*27 + kd*9 + kh*3 + kw];
        else              wv = off_w[((outch-NCLS)*CIN + c)*27 + kd*9 + kh*3 + kw];
      }
      q[i] = tofp8_(wv);
    }
    uint2 p;
    p.x = q[0] | (q[1]<<8) | (q[2]<<16) | (q[3]<<24);
    p.y = q[4] | (q[5]<<8) | (q[6]<<16) | (q[7]<<24);
    *(uint2*)(wA + (size_t)idx*8) = p;
  }
}

// ---------------- Phase A: 32x32x16 fp8 MFMA conv, double-buffered (R16 exact, 79us).
__global__ __launch_bounds__(256, 2) void conv_mfma_kernel(
    const unsigned char* __restrict__ featT,
    const unsigned char* __restrict__ wA,
    const float* __restrict__ cls_b, const float* __restrict__ off_b,
    float* __restrict__ logits_ws,   // [B][5][L]
    float* __restrict__ centers_ws,  // [B][L][4]
    float* __restrict__ bg_sum,
    unsigned* __restrict__ moff_u)
{
  __shared__ uint4 xs4[2*BUFSZ/16];
  __shared__ float bsum[4];
  unsigned char* xs = (unsigned char*)xs4;

  const int tid = threadIdx.x;
  const int lane = tid & 63, hl = tid >> 6;
  const int col = lane & 31, khalf = lane >> 5;
  const int h0 = blockIdx.x*4, d0 = blockIdx.y*4, b = blockIdx.z;
  const bool edge = (d0==0) || (d0==DD_-4) || (h0==0) || (h0==HH_-4);

  for (int idx = tid; idx < 144; idx += 256){
    int buf = idx / 72; int j = idx - buf*72;
    int row = j >> 1, slot = j & 1;
    *(uint4*)(xs + buf*BUFSZ + row*1056 + slot*1040) = make_uint4(0,0,0,0);
  }
  if (edge){
    #pragma unroll 1
    for (int row=0; row<36; ++row){
      int d_ = d0-1+row/6, h_ = h0-1+row-6*(row/6);
      if ((unsigned)d_ < 64u && (unsigned)h_ < 64u) continue;
      if (tid < 128){
        int buf = tid >> 6, wp = (tid & 63) + 1;
        *(uint4*)(xs + buf*BUFSZ + row*1056 + wp*16) = make_uint4(0,0,0,0);
      }
    }
  }

  int soff[9]; int sdst[9]; unsigned svalid = 0;
  #pragma unroll
  for (int it=0; it<9; ++it){
    int row = it*4 + hl;
    int rd = row/6;
    int d_ = d0 - 1 + rd, h_ = h0 - 1 + row - 6*rd;
    bool v = !edge || ((unsigned)d_ < 64u && (unsigned)h_ < 64u);
    if (v) svalid |= (1u<<it);
    int dc = v ? d_ : 0, hc = v ? h_ : 0;
    soff[it] = (dc*4096 + hc*64 + lane)*16;
    sdst[it] = row*1056 + 16;
  }

  floatx16 accA = (floatx16)(0.f);
  floatx16 accB = (floatx16)(0.f);

  const long* wAv = (const long*)wA;
  const int bpoff = hl*1056 + col*16 + khalf*8;

#define STAGE(ccv, bufsel) { \
  const unsigned char* plane = featT + (size_t)(b*4+(ccv))*LL*16; \
  _Pragma("unroll") \
  for (int it=0; it<9; ++it){ \
    if (svalid & (1u<<it)){ \
      __builtin_amdgcn_global_load_lds( \
        (const __attribute__((address_space(1))) void*)(plane + soff[it]), \
        (__attribute__((address_space(3))) void*)(xs + (bufsel)*BUFSZ + sdst[it]), 16, 0, 0); \
    } \
  } }

#define LOADA(dst, ccv, rrv) { \
  _Pragma("unroll") \
  for (int q=0;q<9;++q) dst[q] = wAv[(size_t)(((rrv)*9+q)*4+(ccv))*64 + lane]; }

#define COMPR(areg, rrv, xb) \
  if ((unsigned)(d0-1+(rrv)) < 64u){ \
    const unsigned char* bp = (xb) + bpoff + (rrv)*6336; \
    _Pragma("unroll") \
    for (int kh=0;kh<3;++kh){ \
      if ((unsigned)(h0+hl-1+kh) < 64u){ \
        _Pragma("unroll") \
        for (int kw=0;kw<3;++kw){ \
          long a = areg[kh*3+kw]; \
          long b0 = *(const long*)(bp + kh*1056 + kw*16); \
          accA = __builtin_amdgcn_mfma_f32_32x32x16_fp8_fp8(a, b0, accA, 0,0,0); \
          long b1 = *(const long*)(bp + kh*1056 + kw*16 + 512); \
          accB = __builtin_amdgcn_mfma_f32_32x32x16_fp8_fp8(a, b1, accB, 0,0,0); \
        } } } }

  long aP[9], aQ[9];
  LOADA(aP, 0, 0);
  STAGE(0, 0);
  __syncthreads();

  #pragma unroll 1
  for (int cc=0; cc<4; ++cc){
    if (cc < 3) STAGE(cc+1, (cc+1)&1);
    const unsigned char* xb = xs + (cc&1)*BUFSZ;
    LOADA(aQ, cc, 1);             COMPR(aP, 0, xb);
    LOADA(aP, cc, 2);             COMPR(aQ, 1, xb);
    LOADA(aQ, cc, 3);             COMPR(aP, 2, xb);
    LOADA(aP, cc, 4);             COMPR(aQ, 3, xb);
    LOADA(aQ, cc, 5);             COMPR(aP, 4, xb);
    { int nc = (cc+1)&3; LOADA(aP, nc, 0); }  COMPR(aQ, 5, xb);
    __syncthreads();
  }

  float bg = 0.f, om = 0.f;
  const int h = h0 + hl;
  #pragma unroll
  for (int wh=0; wh<2; ++wh){
    const int w = wh*32 + col;
    #pragma unroll
    for (int dq=0; dq<4; ++dq){
      int d = d0 + dq;
      size_t l = (size_t)d*4096 + (size_t)h*64 + w;
      float v0 = wh ? accB[dq*4+0] : accA[dq*4+0];
      float v1 = wh ? accB[dq*4+1] : accA[dq*4+1];
      float v2 = wh ? accB[dq*4+2] : accA[dq*4+2];
      float v3 = wh ? accB[dq*4+3] : accA[dq*4+3];
      if (khalf == 0){
        float z0 = v0 + cls_b[0]; logits_ws[(size_t)(b*NCLS+0)*LL + l] = z0;
        float z1 = v1 + cls_b[1]; logits_ws[(size_t)(b*NCLS+1)*LL + l] = z1;
        float z2 = v2 + cls_b[2]; logits_ws[(size_t)(b*NCLS+2)*LL + l] = z2;
        float z3 = v3 + cls_b[3]; logits_ws[(size_t)(b*NCLS+3)*LL + l] = z3;
        float p;
        p = sigmoidf_(z0); bg += 0.75f*p*p*softplusf_(z0);
        p = sigmoidf_(z1); bg += 0.75f*p*p*softplusf_(z1);
        p = sigmoidf_(z2); bg += 0.75f*p*p*softplusf_(z2);
        p = sigmoidf_(z3); bg += 0.75f*p*p*softplusf_(z3);
      } else {
        float z4 = v0 + cls_b[4]; logits_ws[(size_t)(b*NCLS+4)*LL + l] = z4;
        float p = sigmoidf_(z4); bg += 0.75f*p*p*softplusf_(z4);
        float o0 = v1 + off_b[0];
        float o1 = v2 + off_b[1];
        float o2 = v3 + off_b[2];
        om = fmaxf(om, fmaxf(fabsf(o0), fmaxf(fabsf(o1), fabsf(o2))));
        float4 ctr;
        ctr.x = ((float)d+0.5f)*2.f + o0;
        ctr.y = ((float)h+0.5f)*2.f + o1;
        ctr.z = ((float)w+0.5f)*2.f + o2;
        ctr.w = 0.f;
        *(float4*)(centers_ws + ((size_t)b*LL + l)*4) = ctr;
      }
    }
  }
  #pragma unroll
  for (int off=32;off;off>>=1){
    bg += __shfl_down(bg, off);
    om = fmaxf(om, __shfl_xor(om, off));
  }
  if (lane == 0){
    bsum[hl] = bg;
    atomicMax(moff_u, __float_as_uint(om));
  }
  __syncthreads();
  if (tid == 0)
    atomicAdd(bg_sum, bsum[0]+bsum[1]+bsum[2]+bsum[3]);
}

// ---------------- Phase B+C: topk slabs, then LAST block (device-scope ticket)
// merges 52->13 per bn and runs the 3-pass finalize. Grid (64, NSLAB) x 256 thr.
__global__ __launch_bounds__(256) void topk_final_kernel(
    const float* __restrict__ logits_ws, const float* __restrict__ centers_ws,
    const float* __restrict__ labels,
    const float* __restrict__ bgz, int* __restrict__ ticket,
    float* __restrict__ pv, int* __restrict__ pi,   // [64][NSLAB][13]
    float* __restrict__ out)
{
  __shared__ float sv2[4*13]; __shared__ int si2[4*13];
  __shared__ int lastFlag;
  // finalize-phase shared
  __shared__ float tvs[64*TOPKK]; __shared__ int tis[64*TOPKK];
  __shared__ float gx[64], gy[64], gz[64], gs[64];
  __shared__ int glab[64], gvalid[64];
  __shared__ int hkey[2048], hcnt[2048], hmin[2048];
  __shared__ unsigned maxA[64], maxI[64];
  __shared__ float accD, accC;

  const int bn = blockIdx.x;
  const int slab = blockIdx.y;
  const int b = bn >> 5, n = bn & 31;
  const int tid = threadIdx.x;

  {
    const float* lb = labels + (b*NMAXG + n)*5;
    const float tx = lb[0], ty = lb[1], tz = lb[2];
    const float cf = lb[3];
    const float sg = lb[4];
    const int lab = (cf == -100.f) ? 0 : (int)cf;
    const float m6 = -3.f/(sg*sg);
    const float moff = __uint_as_float(((const unsigned*)bgz)[1]);
    const float R = 2.6336f*sg + moff + 0.05f;

    int i0d = (int)ceilf((tx - R - 1.f)*0.5f); if (i0d < 0) i0d = 0;
    int i1d = (int)floorf((tx + R - 1.f)*0.5f); if (i1d > 63) i1d = 63;
    int i0h = (int)ceilf((ty - R - 1.f)*0.5f); if (i0h < 0) i0h = 0;
    int i1h = (int)floorf((ty + R - 1.f)*0.5f); if (i1h > 63) i1h = 63;
    int i0w = (int)ceilf((tz - R - 1.f)*0.5f); if (i0w < 0) i0w = 0;
    int i1w = (int)floorf((tz + R - 1.f)*0.5f); if (i1w > 63) i1w = 63;
    int nd = i1d-i0d+1, nh = i1h-i0h+1, nw = i1w-i0w+1;
    int total = (nd>0 && nh>0 && nw>0) ? nd*nh*nw : 0;
    int lo = (total*slab)/NSLAB, hi = (total*(slab+1))/NSLAB;

    const float* lg = logits_ws + (size_t)(b*NCLS + lab)*LL;
    const float* cb = centers_ws + (size_t)b*LL*4;

    float v[13]; int ix[13];
    #pragma unroll
    for (int j=0;j<13;++j){ v[j]=-1.f; ix[j]=0x7fffffff; }

    for (int idx = lo + tid; idx < hi; idx += 256){
      int r = idx;
      int wi = r % nw; r /= nw;
      int hi2 = r % nh; int di = r / nh;
      int l = (i0d+di)*4096 + (i0h+hi2)*64 + (i0w+wi);
      float4 c4 = *(const float4*)(cb + (size_t)l*4);
      float dx = c4.x-tx, dy = c4.y-ty, dz = c4.z-tz;
      float e = m6*(dx*dx + dy*dy + dz*dz);
      if (e < -20.8f) continue;
      float a = sigmoidf_(lg[l]) * expf(e);
      if (a > v[12]){
        float cv = a; int ci = l;
        #pragma unroll
        for (int j=0;j<13;++j){
          bool take = (cv > v[j]) || (cv == v[j] && ci < ix[j]);
          float nv = take ? cv : v[j];  float ov = take ? v[j] : cv;
          int   ni = take ? ci : ix[j]; int   oi = take ? ix[j] : ci;
          v[j]=nv; ix[j]=ni; cv=ov; ci=oi;
        }
      }
    }

    const int lane = tid & 63, wvi = tid >> 6;
    float mv = -2.f; int mi = 0x7fffffff;
    #pragma unroll 1
    for (int k=0;k<13;++k){
      float bv = v[0]; int bi = ix[0]; int bl = lane;
      #pragma unroll
      for (int off=32; off; off>>=1){
        float ov2 = __shfl_xor(bv, off);
        int oi = __shfl_xor(bi, off);
        int ol = __shfl_xor(bl, off);
        if (ov2 > bv || (ov2 == bv && oi < bi)){ bv=ov2; bi=oi; bl=ol; }
      }
      if (lane == k){ mv = bv; mi = bi; }
      if (lane == bl){
        #pragma unroll
        for (int j=0;j<12;++j){ v[j]=v[j+1]; ix[j]=ix[j+1]; }
        v[12] = -2.f; ix[12] = 0x7fffffff;
      }
    }
    if (lane < 13){ sv2[wvi*13+lane] = mv; si2[wvi*13+lane] = mi; }
    __syncthreads();
    if (wvi == 0){
      float v2 = -2.f; int i2 = 0x7fffffff;
      if (lane < 52){ v2 = sv2[lane]; i2 = si2[lane]; }
      #pragma unroll 1
      for (int k=0;k<13;++k){
        float bv = v2; int bi = i2; int bl = lane;
        #pragma unroll
        for (int off=32; off; off>>=1){
          float ov2 = __shfl_xor(bv, off);
          int oi = __shfl_xor(bi, off);
          int ol = __shfl_xor(bl, off);
          if (ov2 > bv || (ov2 == bv && oi < bi)){ bv=ov2; bi=oi; bl=ol; }
        }
        if (lane == 0){
          pv[(bn*NSLAB+slab)*TOPKK + k] = bv;
          pi[(bn*NSLAB+slab)*TOPKK + k] = bi;
        }
        if (lane == bl) v2 = -2.f;
      }
    }
  }

  // ---- last-block ticket (device-scope release/acquire)
  __syncthreads();
  __threadfence();
  if (tid == 0){
    int t = atomicAdd(ticket, 1);
    lastFlag = (t == 64*NSLAB - 1);
  }
  __syncthreads();
  if (!lastFlag) return;
  __threadfence();

  // ---- merge 52 -> top-13 per bn (4 waves x 16 bn), same compare logic as R15
  for (int i=tid;i<2048;i+=256){ hkey[i]=-1; hcnt[i]=0; hmin[i]=0x7fffffff; }
  if (tid<64){
    const float* lb = labels + tid*5;   // tid = b*32+n
    gx[tid]=lb[0]; gy[tid]=lb[1]; gz[tid]=lb[2];
    float cf = lb[3]; gs[tid]=lb[4];
    int val = (cf != -100.f);
    gvalid[tid]=val; glab[tid]= val ? (int)cf : 0;
    maxA[tid]=0u; maxI[tid]=0u;
  }
  if (tid==0){ accD=0.f; accC=0.f; }
  {
    const int lane = tid & 63, wvi = tid >> 6;
    const int NC = NSLAB*TOPKK;      // 52
    #pragma unroll 1
    for (int q=0; q<16; ++q){
      int bnm = wvi*16 + q;
      float v = -2.f; int ixv = 0x7fffffff;
      if (lane < NC){ v = pv[bnm*NC + lane]; ixv = pi[bnm*NC + lane]; }
      #pragma unroll 1
      for (int k=0;k<13;++k){
        float bv = v; int bi = ixv; int bl = lane;
        #pragma unroll
        for (int off=32; off; off>>=1){
          float ov = __shfl_xor(bv, off);
          int oi = __shfl_xor(bi, off);
          int ol = __shfl_xor(bl, off);
          if (ov > bv || (ov == bv && oi < bi)){ bv=ov; bi=oi; bl=ol; }
        }
        if (lane==0){ tvs[bnm*TOPKK+k]=bv; tis[bnm*TOPKK+k]=bi; }
        if (lane==bl) v = -2.f;
      }
    }
  }
  __syncthreads();

  // ---- pass 1: hash insert (cnt + first-entry by min e)
  #pragma unroll 1
  for (int e=tid; e<2*416; e+=256){
    int bq = (e >= 416) ? 1 : 0;
    int eb = e - 416*bq;
    int nn = eb/13; int k = eb - 13*nn;
    float v = tvs[(bq*NMAXG+nn)*TOPKK + k];
    int l = tis[(bq*NMAXG+nn)*TOPKK + k];
    bool ok = gvalid[bq*32+nn] && (v > 1e-9f);
    if (ok){
      unsigned h = (((unsigned)l * 2654435761u) >> 20) & 1023u;
      int slot;
      for (;;){
        int prev = atomicCAS(&hkey[bq*1024 + (int)h], -1, l);
        if (prev == -1 || prev == l){ slot = bq*1024 + (int)h; break; }
        h = (h+1) & 1023u;
      }
      atomicAdd(&hcnt[slot], 1);
      atomicMin(&hmin[slot], e);
    }
  }
  __syncthreads();

  // ---- pass 2: per-gt maxA/maxI from first-entries
  #pragma unroll 1
  for (int e=tid; e<2*416; e+=256){
    int bq = (e >= 416) ? 1 : 0;
    int eb = e - 416*bq;
    int nn = eb/13; int k = eb - 13*nn;
    float v = tvs[(bq*NMAXG+nn)*TOPKK + k];
    int l = tis[(bq*NMAXG+nn)*TOPKK + k];
    if (!(gvalid[bq*32+nn] && (v > 1e-9f))) continue;
    unsigned h = (((unsigned)l * 2654435761u) >> 20) & 1023u;
    while (hkey[bq*1024 + (int)h] != l) h = (h+1) & 1023u;
    int slot = bq*1024 + (int)h;
    if (hmin[slot] != e) continue;
    float px = centers_ws[((size_t)bq*LL + l)*4 + 0];
    float py = centers_ws[((size_t)bq*LL + l)*4 + 1];
    float pz = centers_ws[((size_t)bq*LL + l)*4 + 2];
    int nstar;
    if (hcnt[slot] == 1) nstar = nn;
    else {
      float best = -1.f; int bidx = 0;
      #pragma unroll 1
      for (int n2=0;n2<32;++n2){
        float dx=gx[bq*32+n2]-px, dy=gy[bq*32+n2]-py, dz=gz[bq*32+n2]-pz;
        float d2 = dx*dx+dy*dy+dz*dz;
        float io = expf(-d2/(2.f*gs[bq*32+n2]*gs[bq*32+n2]));
        if (io > best){ best=io; bidx=n2; }
      }
      nstar = bidx;
    }
    int gi = bq*32 + nstar;
    float dx=gx[gi]-px, dy=gy[gi]-py, dz=gz[gi]-pz;
    float d2 = dx*dx+dy*dy+dz*dz;
    float sgv = gs[gi];
    float iou = expf(-d2/(2.f*sgv*sgv));
    float z = logits_ws[(size_t)(bq*NCLS + glab[gi])*LL + l];
    float a = sigmoidf_(z) * expf(-3.f*d2/(sgv*sgv));
    atomicMax(&maxA[gi], __float_as_uint(a));
    atomicMax(&maxI[gi], __float_as_uint(iou));
  }
  __syncthreads();

  // ---- pass 3: accumulate corrections + reg loss + denominator
  #pragma unroll 1
  for (int e=tid; e<2*416; e+=256){
    int bq = (e >= 416) ? 1 : 0;
    int eb = e - 416*bq;
    int nn = eb/13; int k = eb - 13*nn;
    float v = tvs[(bq*NMAXG+nn)*TOPKK + k];
    int l = tis[(bq*NMAXG+nn)*TOPKK + k];
    if (!(gvalid[bq*32+nn] && (v > 1e-9f))) continue;
    unsigned h = (((unsigned)l * 2654435761u) >> 20) & 1023u;
    while (hkey[bq*1024 + (int)h] != l) h = (h+1) & 1023u;
    int slot = bq*1024 + (int)h;
    if (hmin[slot] != e) continue;
    float px = centers_ws[((size_t)bq*LL + l)*4 + 0];
    float py = centers_ws[((size_t)bq*LL + l)*4 + 1];
    float pz = centers_ws[((size_t)bq*LL + l)*4 + 2];
    int nstar;
    if (hcnt[slot] == 1) nstar = nn;
    else {
      float best = -1.f; int bidx = 0;
      #pragma unroll 1
      for (int n2=0;n2<32;++n2){
        float dx=gx[bq*32+n2]-px, dy=gy[bq*32+n2]-py, dz=gz[bq*32+n2]-pz;
        float d2 = dx*dx+dy*dy+dz*dz;
        float io = expf(-d2/(2.f*gs[bq*32+n2]*gs[bq*32+n2]));
        if (io > best){ best=io; bidx=n2; }
      }
      nstar = bidx;
    }
    int gi = bq*32 + nstar;
    float dx=gx[gi]-px, dy=gy[gi]-py, dz=gz[gi]-pz;
    float d2 = dx*dx+dy*dy+dz*dz;
    float sgv = gs[gi];
    float iou = expf(-d2/(2.f*sgv*sgv));
    float z = logits_ws[(size_t)(bq*NCLS + glab[gi])*LL + l];
    float a = sigmoidf_(z) * expf(-3.f*d2/(sgv*sgv));
    float mA = __uint_as_float(maxA[gi]);
    float mI = __uint_as_float(maxI[gi]);
    float score = a*mI/(mA + 1e-9f);
    float p = sigmoidf_(z);
    float t2 = log1pf(expf(-fabsf(z)));
    float spz = fmaxf(z,0.f) + t2;
    float spm = fmaxf(-z,0.f) + t2;
    float corr = score*(score*spm + (1.f-score)*spz) - 0.75f*p*p*spz;
    float reg  = (1.f - iou)*score;
    atomicAdd(&accD, score);
    atomicAdd(&accC, corr + reg);
  }
  __syncthreads();
  if (tid==0) out[0] = (bgz[0] + accC) / accD;
}

extern "C" void kernel_launch(void* const* d_in, const int* in_sizes, int n_in,
                              void* d_out, int out_size, void* d_ws, size_t ws_size,
                              hipStream_t stream) {
  const float* feat  = (const float*)d_in[0];
  const float* cls_w = (const float*)d_in[1];
  const float* cls_b = (const float*)d_in[2];
  const float* off_w = (const float*)d_in[3];
  const float* off_b = (const float*)d_in[4];
  const float* labels= (const float*)d_in[5];
  float* out = (float*)d_out;

  float* logits_ws  = (float*)d_ws;                              // 2*5*L f32
  float* centers_ws = logits_ws + (size_t)NB*NCLS*LL;            // 2*L*4 f32
  float* pv = centers_ws + (size_t)NB*LL*4;                      // 64*NSLAB*13
  int*   pi = (int*)(pv + 64*NSLAB*TOPKK);
  float* bg = (float*)(pi + 64*NSLAB*TOPKK);                     // [0]=bg,[1]=moff,[4]=ticket
  unsigned char* wA = (unsigned char*)(bg + 16);                 // 216*64*8 fp8 bytes
  unsigned char* featT = wA + 216*64*8;                          // 33.5MB

  transpose_kernel<<<dim3(64,16,2), 256, 0, stream>>>(
      feat, featT, cls_w, off_w, wA, bg);
  conv_mfma_kernel<<<dim3(16,16,2), 256, 0, stream>>>(
      featT, wA, cls_b, off_b, logits_ws, centers_ws, bg, (unsigned*)(bg+1));
  topk_final_kernel<<<dim3(64,NSLAB), 256, 0, stream>>>(
      logits_ws, centers_ws, labels, bg, (int*)(bg+4), pv, pi, out);
}

// Round 18
// 163.227 us; speedup vs baseline: 1.7986x; 1.7986x over previous
//
#include <hip/hip_runtime.h>
#include <math.h>

#define NB 2
#define CIN 64
#define DD_ 64
#define HH_ 64
#define WW_ 64
#define NCLS 5
#define LL (DD_*HH_*WW_)   /* 262144 */
#define NMAXG 32
#define TOPKK 13
#define NSLAB 4
#define BUFSZ 38016        /* 36 rows * 66 wp * 16 fp8 bytes */

typedef __attribute__((ext_vector_type(16))) float floatx16;

__device__ __forceinline__ float softplusf_(float z){
  return fmaxf(z, 0.f) + log1pf(expf(-fabsf(z)));
}
__device__ __forceinline__ float sigmoidf_(float z){
  return 1.f/(1.f + expf(-z));
}
// fp32 -> fp8 e4m3fn, RNE, saturate to 448
__device__ __forceinline__ unsigned tofp8_(float x){
  unsigned u = __float_as_uint(x);
  unsigned sign = (u >> 24) & 0x80u;
  unsigned a = u & 0x7FFFFFFFu;
  if (a >= 0x43E00000u) return sign | 0x7Eu;
  if (a < 0x3C800000u){
    float fa = __uint_as_float(a);
    int m = (int)rintf(fa * 512.f);
    return sign | (unsigned)m;
  }
  unsigned bb = a + 0x7FFFFu + ((a >> 20) & 1u);
  unsigned e8 = ((bb >> 23) & 0xFFu) - 120u;
  unsigned m8 = (bb >> 20) & 7u;
  if (e8 > 15u || (e8 == 15u && m8 > 6u)) return sign | 0x7Eu;
  return sign | (e8 << 3) | m8;
}

// ---------------- Phase 0: fused transpose fp32 NCDHW -> fp8 [b][cc][voxel][16c]
// + weight->fp8 A-fragment build + bg/moff zero init.
__global__ __launch_bounds__(256) void transpose_kernel(
    const float* __restrict__ feat, unsigned char* __restrict__ featT,
    const float* __restrict__ cls_w, const float* __restrict__ off_w,
    unsigned char* __restrict__ wA, float* __restrict__ bgz)
{
  const int t = threadIdx.x;
  const int w = t & 63;
  const int hh = t >> 6;                 // 0..3
  const int d = blockIdx.x;
  const int h = blockIdx.y*4 + hh;
  const int b = blockIdx.z;
  const float* src = feat + (size_t)b*CIN*LL + (size_t)d*4096 + (size_t)h*64 + w;
  const size_t sp = (size_t)d*4096 + (size_t)h*64 + w;
  #pragma unroll
  for (int cc=0; cc<4; ++cc){
    unsigned q[16];
    #pragma unroll
    for (int j=0;j<16;++j) q[j] = tofp8_(src[(size_t)(cc*16+j)*LL]);
    uint4 p;
    p.x = q[0] | (q[1]<<8) | (q[2]<<16) | (q[3]<<24);
    p.y = q[4] | (q[5]<<8) | (q[6]<<16) | (q[7]<<24);
    p.z = q[8] | (q[9]<<8) | (q[10]<<16) | (q[11]<<24);
    p.w = q[12] | (q[13]<<8) | (q[14]<<16) | (q[15]<<24);
    *(uint4*)(featT + ((size_t)(b*4+cc)*LL + sp)*16) = p;
  }
  if (blockIdx.z == 0 && blockIdx.y == 0 && blockIdx.x < 54){
    if (blockIdx.x == 0 && t < 8) bgz[t] = 0.f;   // bg, moff, pads
    int idx = blockIdx.x*256 + t;
    int slice = idx >> 6; int lane = idx & 63;
    int cc = slice & 3; int r = slice >> 2;       // r = rr*9 + kh*3 + kw
    int kw = r % 3; int r2 = r / 3;
    int kh = r2 % 3; int rr = r2 / 3;             // 0..5
    int m = lane & 31, khalf = lane >> 5;
    int outch = m & 7;
    int kd = rr - (m >> 3);
    unsigned q[8];
    #pragma unroll
    for (int i=0;i<8;++i){
      int c = cc*16 + khalf*8 + i;
      float wv = 0.f;
      if (kd >= 0 && kd <= 2){
        if (outch < NCLS) wv = cls_w[(outch*CIN + c)*27 + kd*9 + kh*3 + kw];
        else              wv = off_w[((outch-NCLS)*CIN + c)*27 + kd*9 + kh*3 + kw];
      }
      q[i] = tofp8_(wv);
    }
    uint2 p;
    p.x = q[0] | (q[1]<<8) | (q[2]<<16) | (q[3]<<24);
    p.y = q[4] | (q[5]<<8) | (q[6]<<16) | (q[7]<<24);
    *(uint2*)(wA + (size_t)idx*8) = p;
  }
}

// ---------------- Phase A: 32x32x16 fp8 MFMA conv, SINGLE 38KB buffer, 4 blocks/CU.
// Block 4d x 4h x 64w, 256 thr (4 waves, wave = h-line). TLP hides the barrier drain.
__global__ __launch_bounds__(256, 4) void conv_mfma_kernel(
    const unsigned char* __restrict__ featT,
    const unsigned char* __restrict__ wA,
    const float* __restrict__ cls_b, const float* __restrict__ off_b,
    float* __restrict__ logits_ws,   // [B][5][L]
    float* __restrict__ centers_ws,  // [B][L][4]
    float* __restrict__ bg_sum,
    unsigned* __restrict__ moff_u)
{
  __shared__ uint4 xs4[BUFSZ/16];     // 38016 B
  __shared__ float bsum[4];
  unsigned char* xs = (unsigned char*)xs4;

  const int tid = threadIdx.x;
  const int lane = tid & 63, hl = tid >> 6;
  const int col = lane & 31, khalf = lane >> 5;
  const int h0 = blockIdx.x*4, d0 = blockIdx.y*4, b = blockIdx.z;
  const bool edge = (d0==0) || (d0==DD_-4) || (h0==0) || (h0==HH_-4);

  // zero w-halo slots (wp 0 and 65): 36 rows x 2 slots
  if (tid < 72){
    int row = tid >> 1, slot = tid & 1;
    *(uint4*)(xs + row*1056 + slot*1040) = make_uint4(0,0,0,0);
  }
  // edge blocks: zero OOB rows (never staged)
  if (edge){
    #pragma unroll 1
    for (int row=0; row<36; ++row){
      int d_ = d0-1+row/6, h_ = h0-1+row-6*(row/6);
      if ((unsigned)d_ < 64u && (unsigned)h_ < 64u) continue;
      if (tid < 64){
        *(uint4*)(xs + row*1056 + (tid+1)*16) = make_uint4(0,0,0,0);
      }
    }
  }

  int soff[9]; int sdst[9]; unsigned svalid = 0;
  #pragma unroll
  for (int it=0; it<9; ++it){
    int row = it*4 + hl;
    int rd = row/6;
    int d_ = d0 - 1 + rd, h_ = h0 - 1 + row - 6*rd;
    bool v = !edge || ((unsigned)d_ < 64u && (unsigned)h_ < 64u);
    if (v) svalid |= (1u<<it);
    int dc = v ? d_ : 0, hc = v ? h_ : 0;
    soff[it] = (dc*4096 + hc*64 + lane)*16;
    sdst[it] = row*1056 + 16;
  }

  floatx16 accA = (floatx16)(0.f);
  floatx16 accB = (floatx16)(0.f);

  const long* wAv = (const long*)wA;
  const int bpoff = hl*1056 + col*16 + khalf*8;

#define STAGE(ccv) { \
  const unsigned char* plane = featT + (size_t)(b*4+(ccv))*LL*16; \
  _Pragma("unroll") \
  for (int it=0; it<9; ++it){ \
    if (svalid & (1u<<it)){ \
      __builtin_amdgcn_global_load_lds( \
        (const __attribute__((address_space(1))) void*)(plane + soff[it]), \
        (__attribute__((address_space(3))) void*)(xs + sdst[it]), 16, 0, 0); \
    } \
  } }

#define LOADA(dst, ccv, rrv) { \
  _Pragma("unroll") \
  for (int q=0;q<9;++q) dst[q] = wAv[(size_t)(((rrv)*9+q)*4+(ccv))*64 + lane]; }

#define COMPR(areg, rrv) \
  if ((unsigned)(d0-1+(rrv)) < 64u){ \
    const unsigned char* bp = xs + bpoff + (rrv)*6336; \
    _Pragma("unroll") \
    for (int kh=0;kh<3;++kh){ \
      if ((unsigned)(h0+hl-1+kh) < 64u){ \
        _Pragma("unroll") \
        for (int kw=0;kw<3;++kw){ \
          long a = areg[kh*3+kw]; \
          long b0 = *(const long*)(bp + kh*1056 + kw*16); \
          accA = __builtin_amdgcn_mfma_f32_32x32x16_fp8_fp8(a, b0, accA, 0,0,0); \
          long b1 = *(const long*)(bp + kh*1056 + kw*16 + 512); \
          accB = __builtin_amdgcn_mfma_f32_32x32x16_fp8_fp8(a, b1, accB, 0,0,0); \
        } } } }

  long aP[9], aQ[9];
  LOADA(aP, 0, 0);

  #pragma unroll 1
  for (int cc=0; cc<4; ++cc){
    if (cc) __syncthreads();
    STAGE(cc);
    __syncthreads();
    LOADA(aQ, cc, 1);             COMPR(aP, 0);
    LOADA(aP, cc, 2);             COMPR(aQ, 1);
    LOADA(aQ, cc, 3);             COMPR(aP, 2);
    LOADA(aP, cc, 4);             COMPR(aQ, 3);
    LOADA(aQ, cc, 5);             COMPR(aP, 4);
    { int nc = (cc+1)&3; LOADA(aP, nc, 0); }  COMPR(aQ, 5);
  }

  float bg = 0.f, om = 0.f;
  const int h = h0 + hl;
  #pragma unroll
  for (int wh=0; wh<2; ++wh){
    const int w = wh*32 + col;
    #pragma unroll
    for (int dq=0; dq<4; ++dq){
      int d = d0 + dq;
      size_t l = (size_t)d*4096 + (size_t)h*64 + w;
      float v0 = wh ? accB[dq*4+0] : accA[dq*4+0];
      float v1 = wh ? accB[dq*4+1] : accA[dq*4+1];
      float v2 = wh ? accB[dq*4+2] : accA[dq*4+2];
      float v3 = wh ? accB[dq*4+3] : accA[dq*4+3];
      if (khalf == 0){
        float z0 = v0 + cls_b[0]; logits_ws[(size_t)(b*NCLS+0)*LL + l] = z0;
        float z1 = v1 + cls_b[1]; logits_ws[(size_t)(b*NCLS+1)*LL + l] = z1;
        float z2 = v2 + cls_b[2]; logits_ws[(size_t)(b*NCLS+2)*LL + l] = z2;
        float z3 = v3 + cls_b[3]; logits_ws[(size_t)(b*NCLS+3)*LL + l] = z3;
        float p;
        p = sigmoidf_(z0); bg += 0.75f*p*p*softplusf_(z0);
        p = sigmoidf_(z1); bg += 0.75f*p*p*softplusf_(z1);
        p = sigmoidf_(z2); bg += 0.75f*p*p*softplusf_(z2);
        p = sigmoidf_(z3); bg += 0.75f*p*p*softplusf_(z3);
      } else {
        float z4 = v0 + cls_b[4]; logits_ws[(size_t)(b*NCLS+4)*LL + l] = z4;
        float p = sigmoidf_(z4); bg += 0.75f*p*p*softplusf_(z4);
        float o0 = v1 + off_b[0];
        float o1 = v2 + off_b[1];
        float o2 = v3 + off_b[2];
        om = fmaxf(om, fmaxf(fabsf(o0), fmaxf(fabsf(o1), fabsf(o2))));
        float4 ctr;
        ctr.x = ((float)d+0.5f)*2.f + o0;
        ctr.y = ((float)h+0.5f)*2.f + o1;
        ctr.z = ((float)w+0.5f)*2.f + o2;
        ctr.w = 0.f;
        *(float4*)(centers_ws + ((size_t)b*LL + l)*4) = ctr;
      }
    }
  }
  #pragma unroll
  for (int off=32;off;off>>=1){
    bg += __shfl_down(bg, off);
    om = fmaxf(om, __shfl_xor(om, off));
  }
  if (lane == 0){
    bsum[hl] = bg;
    atomicMax(moff_u, __float_as_uint(om));
  }
  __syncthreads();
  if (tid == 0)
    atomicAdd(bg_sum, bsum[0]+bsum[1]+bsum[2]+bsum[3]);
}

// ---------------- Phase B: bounding-box top-13, NSLAB slabs per (b,n). Grid (64, NSLAB).
__global__ __launch_bounds__(256) void topk_box_kernel(
    const float* __restrict__ logits_ws, const float* __restrict__ centers_ws,
    const float* __restrict__ labels,
    const unsigned* __restrict__ moff_u,
    float* __restrict__ pv, int* __restrict__ pi)   // [64][NSLAB][13]
{
  const int bn = blockIdx.x;
  const int slab = blockIdx.y;
  const int b = bn >> 5, n = bn & 31;
  const int tid = threadIdx.x;

  const float* lb = labels + (b*NMAXG + n)*5;
  const float tx = lb[0], ty = lb[1], tz = lb[2];
  const float cf = lb[3];
  const float sg = lb[4];
  const int lab = (cf == -100.f) ? 0 : (int)cf;
  const float m6 = -3.f/(sg*sg);
  const float moff = __uint_as_float(*moff_u);
  const float R = 2.6336f*sg + moff + 0.05f;

  int i0d = (int)ceilf((tx - R - 1.f)*0.5f); if (i0d < 0) i0d = 0;
  int i1d = (int)floorf((tx + R - 1.f)*0.5f); if (i1d > 63) i1d = 63;
  int i0h = (int)ceilf((ty - R - 1.f)*0.5f); if (i0h < 0) i0h = 0;
  int i1h = (int)floorf((ty + R - 1.f)*0.5f); if (i1h > 63) i1h = 63;
  int i0w = (int)ceilf((tz - R - 1.f)*0.5f); if (i0w < 0) i0w = 0;
  int i1w = (int)floorf((tz + R - 1.f)*0.5f); if (i1w > 63) i1w = 63;
  int nd = i1d-i0d+1, nh = i1h-i0h+1, nw = i1w-i0w+1;
  int total = (nd>0 && nh>0 && nw>0) ? nd*nh*nw : 0;
  int lo = (total*slab)/NSLAB, hi = (total*(slab+1))/NSLAB;

  const float* lg = logits_ws + (size_t)(b*NCLS + lab)*LL;
  const float* cb = centers_ws + (size_t)b*LL*4;

  float v[13]; int ix[13];
  #pragma unroll
  for (int j=0;j<13;++j){ v[j]=-1.f; ix[j]=0x7fffffff; }

  for (int idx = lo + tid; idx < hi; idx += 256){
    int r = idx;
    int wi = r % nw; r /= nw;
    int hi2 = r % nh; int di = r / nh;
    int l = (i0d+di)*4096 + (i0h+hi2)*64 + (i0w+wi);
    float4 c4 = *(const float4*)(cb + (size_t)l*4);
    float dx = c4.x-tx, dy = c4.y-ty, dz = c4.z-tz;
    float e = m6*(dx*dx + dy*dy + dz*dz);
    if (e < -20.8f) continue;
    float a = sigmoidf_(lg[l]) * expf(e);
    if (a > v[12]){
      float cv = a; int ci = l;
      #pragma unroll
      for (int j=0;j<13;++j){
        bool take = (cv > v[j]) || (cv == v[j] && ci < ix[j]);
        float nv = take ? cv : v[j];  float ov = take ? v[j] : cv;
        int   ni = take ? ci : ix[j]; int   oi = take ? ix[j] : ci;
        v[j]=nv; ix[j]=ni; cv=ov; ci=oi;
      }
    }
  }

  const int lane = tid & 63, wvi = tid >> 6;
  float mv = -2.f; int mi = 0x7fffffff;
  #pragma unroll 1
  for (int k=0;k<13;++k){
    float bv = v[0]; int bi = ix[0]; int bl = lane;
    #pragma unroll
    for (int off=32; off; off>>=1){
      float ov2 = __shfl_xor(bv, off);
      int oi = __shfl_xor(bi, off);
      int ol = __shfl_xor(bl, off);
      if (ov2 > bv || (ov2 == bv && oi < bi)){ bv=ov2; bi=oi; bl=ol; }
    }
    if (lane == k){ mv = bv; mi = bi; }
    if (lane == bl){
      #pragma unroll
      for (int j=0;j<12;++j){ v[j]=v[j+1]; ix[j]=ix[j+1]; }
      v[12] = -2.f; ix[12] = 0x7fffffff;
    }
  }
  __shared__ float sv2[4*13]; __shared__ int si2[4*13];
  if (lane < 13){ sv2[wvi*13+lane] = mv; si2[wvi*13+lane] = mi; }
  __syncthreads();
  if (wvi == 0){
    float v2 = -2.f; int i2 = 0x7fffffff;
    if (lane < 52){ v2 = sv2[lane]; i2 = si2[lane]; }
    #pragma unroll 1
    for (int k=0;k<13;++k){
      float bv = v2; int bi = i2; int bl = lane;
      #pragma unroll
      for (int off=32; off; off>>=1){
        float ov2 = __shfl_xor(bv, off);
        int oi = __shfl_xor(bi, off);
        int ol = __shfl_xor(bl, off);
        if (ov2 > bv || (ov2 == bv && oi < bi)){ bv=ov2; bi=oi; bl=ol; }
      }
      if (lane == 0){
        pv[(bn*NSLAB+slab)*TOPKK + k] = bv;
        pi[(bn*NSLAB+slab)*TOPKK + k] = bi;
      }
      if (lane == bl) v2 = -2.f;
    }
  }
}

// ---------------- Phase B2: merge NSLAB partials -> top-13 per (b,n). 64 blocks x 64 thr.
__global__ __launch_bounds__(64) void topk_merge_kernel(
    const float* __restrict__ pv, const int* __restrict__ pi,
    float* __restrict__ tv, int* __restrict__ ti)
{
  const int bn = blockIdx.x;
  const int t = threadIdx.x;       // 64
  const int NC = NSLAB*TOPKK;      // 52
  float v = -2.f; int ix = 0x7fffffff;
  if (t < NC){ v = pv[bn*NC + t]; ix = pi[bn*NC + t]; }
  #pragma unroll 1
  for (int k=0;k<13;++k){
    float bv = v; int bi = ix; int bl = t;
    #pragma unroll
    for (int off=32; off; off>>=1){
      float ov = __shfl_xor(bv, off);
      int oi = __shfl_xor(bi, off);
      int ol = __shfl_xor(bl, off);
      if (ov > bv || (ov == bv && oi < bi)){ bv=ov; bi=oi; bl=ol; }
    }
    if (t==0){ tv[bn*TOPKK+k]=bv; ti[bn*TOPKK+k]=bi; }
    if (t==bl) v = -2.f;
  }
}

// ---------------- Phase C: both batches in one 1024-thread pass, LDS hash table
__global__ __launch_bounds__(1024) void finalize_kernel(
    const float* __restrict__ logits_ws, const float* __restrict__ centers_ws,
    const float* __restrict__ labels,
    const float* __restrict__ tv, const int* __restrict__ ti,
    const float* __restrict__ bg_sum, float* __restrict__ out)
{
  const int tid = threadIdx.x;   // 1024
  __shared__ float gx[64], gy[64], gz[64], gs[64];
  __shared__ int glab[64], gvalid[64];
  __shared__ int hkey[2048], hcnt[2048], hmin[2048];
  __shared__ unsigned maxA[64], maxI[64];
  __shared__ float accD, accC;
  if (tid==0){ accD=0.f; accC=0.f; }
  for (int i=tid;i<2048;i+=1024){ hkey[i]=-1; hcnt[i]=0; hmin[i]=0x7fffffff; }
  if (tid<64){
    const float* lb = labels + tid*5;   // tid = b*32+n
    gx[tid]=lb[0]; gy[tid]=lb[1]; gz[tid]=lb[2];
    float cf = lb[3]; gs[tid]=lb[4];
    int val = (cf != -100.f);
    gvalid[tid]=val; glab[tid]= val ? (int)cf : 0;
    maxA[tid]=0u; maxI[tid]=0u;
  }
  __syncthreads();

  const int e = tid;
  bool ok = false; int l = -1; int n = 0; int b = 0;
  if (e < 2*416){
    b = (e >= 416) ? 1 : 0;
    int eb = e - 416*b;
    n = eb/13; int k = eb - 13*n;
    float v = tv[(b*NMAXG+n)*TOPKK + k];
    l = ti[(b*NMAXG+n)*TOPKK + k];
    ok = gvalid[b*32+n] && (v > 1e-9f);
  }
  int slot = -1;
  if (ok){
    unsigned h = (((unsigned)l * 2654435761u) >> 20) & 1023u;
    for (;;){
      int prev = atomicCAS(&hkey[b*1024 + h], -1, l);
      if (prev == -1 || prev == l){ slot = b*1024 + (int)h; break; }
      h = (h+1) & 1023u;
    }
    atomicAdd(&hcnt[slot], 1);
    atomicMin(&hmin[slot], e);
  }
  __syncthreads();

  bool first = ok && (hmin[slot] == e);
  float a=0.f, iou=0.f; int nstar=0;
  if (first){
    float px = centers_ws[((size_t)b*LL + l)*4 + 0];
    float py = centers_ws[((size_t)b*LL + l)*4 + 1];
    float pz = centers_ws[((size_t)b*LL + l)*4 + 2];
    if (hcnt[slot] == 1){
      nstar = n;
    } else {
      float best = -1.f; int bidx = 0;
      #pragma unroll 1
      for (int nn=0;nn<32;++nn){
        float dx=gx[b*32+nn]-px, dy=gy[b*32+nn]-py, dz=gz[b*32+nn]-pz;
        float d2 = dx*dx+dy*dy+dz*dz;
        float io = expf(-d2/(2.f*gs[b*32+nn]*gs[b*32+nn]));
        if (io > best){ best=io; bidx=nn; }
      }
      nstar = bidx;
    }
    int gi = b*32 + nstar;
    float dx=gx[gi]-px, dy=gy[gi]-py, dz=gz[gi]-pz;
    float d2 = dx*dx+dy*dy+dz*dz;
    float sgv = gs[gi];
    iou = expf(-d2/(2.f*sgv*sgv));
    float z = logits_ws[(size_t)(b*NCLS + glab[gi])*LL + l];
    a = sigmoidf_(z) * expf(-3.f*d2/(sgv*sgv));
    atomicMax(&maxA[gi], __float_as_uint(a));
    atomicMax(&maxI[gi], __float_as_uint(iou));
  }
  __syncthreads();

  if (first){
    int gi = b*32 + nstar;
    float mA = __uint_as_float(maxA[gi]);
    float mI = __uint_as_float(maxI[gi]);
    float score = a*mI/(mA + 1e-9f);
    float z = logits_ws[(size_t)(b*NCLS + glab[gi])*LL + l];
    float p = sigmoidf_(z);
    float t2 = log1pf(expf(-fabsf(z)));
    float spz = fmaxf(z,0.f) + t2;
    float spm = fmaxf(-z,0.f) + t2;
    float corr = score*(score*spm + (1.f-score)*spz) - 0.75f*p*p*spz;
    float reg  = (1.f - iou)*score;
    atomicAdd(&accD, score);
    atomicAdd(&accC, corr + reg);
  }
  __syncthreads();
  if (tid==0) out[0] = (bg_sum[0] + accC) / accD;
}

extern "C" void kernel_launch(void* const* d_in, const int* in_sizes, int n_in,
                              void* d_out, int out_size, void* d_ws, size_t ws_size,
                              hipStream_t stream) {
  const float* feat  = (const float*)d_in[0];
  const float* cls_w = (const float*)d_in[1];
  const float* cls_b = (const float*)d_in[2];
  const float* off_w = (const float*)d_in[3];
  const float* off_b = (const float*)d_in[4];
  const float* labels= (const float*)d_in[5];
  float* out = (float*)d_out;

  float* logits_ws  = (float*)d_ws;                              // 2*5*L f32
  float* centers_ws = logits_ws + (size_t)NB*NCLS*LL;            // 2*L*4 f32
  float* tv = centers_ws + (size_t)NB*LL*4;                      // 64*13
  int*   ti = (int*)(tv + 64*TOPKK);
  float* pv = (float*)(ti + 64*TOPKK);                           // 64*NSLAB*13
  int*   pi = (int*)(pv + 64*NSLAB*TOPKK);
  float* bg = (float*)(pi + 64*NSLAB*TOPKK);                     // [0]=bg,[1]=moff
  unsigned char* wA = (unsigned char*)(bg + 16);                 // 216*64*8 fp8 bytes
  unsigned char* featT = wA + 216*64*8;                          // 33.5MB

  transpose_kernel<<<dim3(64,16,2), 256, 0, stream>>>(
      feat, featT, cls_w, off_w, wA, bg);
  conv_mfma_kernel<<<dim3(16,16,2), 256, 0, stream>>>(
      featT, wA, cls_b, off_b, logits_ws, centers_ws, bg, (unsigned*)(bg+1));
  topk_box_kernel<<<dim3(64,NSLAB), 256, 0, stream>>>(
      logits_ws, centers_ws, labels, (const unsigned*)(bg+1), pv, pi);
  topk_merge_kernel<<<64, 64, 0, stream>>>(pv, pi, tv, ti);
  finalize_kernel<<<1, 1024, 0, stream>>>(
      logits_ws, centers_ws, labels, tv, ti, bg, out);
}

// Round 19
// 162.218 us; speedup vs baseline: 1.8098x; 1.0062x over previous
//
#include <hip/hip_runtime.h>
#include <math.h>

#define NB 2
#define CIN 64
#define DD_ 64
#define HH_ 64
#define WW_ 64
#define NCLS 5
#define LL (DD_*HH_*WW_)   /* 262144 */
#define NMAXG 32
#define TOPKK 13
#define NSLAB 4
#define BUFSZ 38016        /* 36 rows * 66 wp * 16 fp8 bytes */

typedef __attribute__((ext_vector_type(16))) float floatx16;

__device__ __forceinline__ float softplusf_(float z){
  return fmaxf(z, 0.f) + log1pf(expf(-fabsf(z)));
}
__device__ __forceinline__ float sigmoidf_(float z){
  return 1.f/(1.f + expf(-z));
}
// fp32 -> fp8 e4m3fn, RNE, saturate to 448
__device__ __forceinline__ unsigned tofp8_(float x){
  unsigned u = __float_as_uint(x);
  unsigned sign = (u >> 24) & 0x80u;
  unsigned a = u & 0x7FFFFFFFu;
  if (a >= 0x43E00000u) return sign | 0x7Eu;
  if (a < 0x3C800000u){
    float fa = __uint_as_float(a);
    int m = (int)rintf(fa * 512.f);
    return sign | (unsigned)m;
  }
  unsigned bb = a + 0x7FFFFu + ((a >> 20) & 1u);
  unsigned e8 = ((bb >> 23) & 0xFFu) - 120u;
  unsigned m8 = (bb >> 20) & 7u;
  if (e8 > 15u || (e8 == 15u && m8 > 6u)) return sign | 0x7Eu;
  return sign | (e8 << 3) | m8;
}

// ---------------- Phase 0: fused transpose fp32 NCDHW -> fp8 [b][cc][voxel][16c]
// + weight->fp8 A-fragment build + bg/moff zero init.
__global__ __launch_bounds__(256) void transpose_kernel(
    const float* __restrict__ feat, unsigned char* __restrict__ featT,
    const float* __restrict__ cls_w, const float* __restrict__ off_w,
    unsigned char* __restrict__ wA, float* __restrict__ bgz)
{
  const int t = threadIdx.x;
  const int w = t & 63;
  const int hh = t >> 6;                 // 0..3
  const int d = blockIdx.x;
  const int h = blockIdx.y*4 + hh;
  const int b = blockIdx.z;
  const float* src = feat + (size_t)b*CIN*LL + (size_t)d*4096 + (size_t)h*64 + w;
  const size_t sp = (size_t)d*4096 + (size_t)h*64 + w;
  #pragma unroll
  for (int cc=0; cc<4; ++cc){
    unsigned q[16];
    #pragma unroll
    for (int j=0;j<16;++j) q[j] = tofp8_(src[(size_t)(cc*16+j)*LL]);
    uint4 p;
    p.x = q[0] | (q[1]<<8) | (q[2]<<16) | (q[3]<<24);
    p.y = q[4] | (q[5]<<8) | (q[6]<<16) | (q[7]<<24);
    p.z = q[8] | (q[9]<<8) | (q[10]<<16) | (q[11]<<24);
    p.w = q[12] | (q[13]<<8) | (q[14]<<16) | (q[15]<<24);
    *(uint4*)(featT + ((size_t)(b*4+cc)*LL + sp)*16) = p;
  }
  if (blockIdx.z == 0 && blockIdx.y == 0 && blockIdx.x < 54){
    if (blockIdx.x == 0 && t < 8) bgz[t] = 0.f;   // bg, moff, pads
    int idx = blockIdx.x*256 + t;
    int slice = idx >> 6; int lane = idx & 63;
    int cc = slice & 3; int r = slice >> 2;       // r = rr*9 + kh*3 + kw
    int kw = r % 3; int r2 = r / 3;
    int kh = r2 % 3; int rr = r2 / 3;             // 0..5
    int m = lane & 31, khalf = lane >> 5;
    int outch = m & 7;
    int kd = rr - (m >> 3);
    unsigned q[8];
    #pragma unroll
    for (int i=0;i<8;++i){
      int c = cc*16 + khalf*8 + i;
      float wv = 0.f;
      if (kd >= 0 && kd <= 2){
        if (outch < NCLS) wv = cls_w[(outch*CIN + c)*27 + kd*9 + kh*3 + kw];
        else              wv = off_w[((outch-NCLS)*CIN + c)*27 + kd*9 + kh*3 + kw];
      }
      q[i] = tofp8_(wv);
    }
    uint2 p;
    p.x = q[0] | (q[1]<<8) | (q[2]<<16) | (q[3]<<24);
    p.y = q[4] | (q[5]<<8) | (q[6]<<16) | (q[7]<<24);
    *(uint2*)(wA + (size_t)idx*8) = p;
  }
}

// ---------------- Phase A: 32x32x16 fp8 MFMA conv, 6 accumulator chains (by kh).
// Block 4d x 4h x 64w, 256 thr (4 waves, wave = h-line). 38KB LDS.
__global__ __launch_bounds__(256, 2) void conv_mfma_kernel(
    const unsigned char* __restrict__ featT,
    const unsigned char* __restrict__ wA,
    const float* __restrict__ cls_b, const float* __restrict__ off_b,
    float* __restrict__ logits_ws,   // [B][5][L]
    float* __restrict__ centers_ws,  // [B][L][4]
    float* __restrict__ bg_sum,
    unsigned* __restrict__ moff_u)
{
  __shared__ uint4 xs4[BUFSZ/16];     // 38016 B
  __shared__ float bsum[4];
  unsigned char* xs = (unsigned char*)xs4;

  const int tid = threadIdx.x;
  const int lane = tid & 63, hl = tid >> 6;
  const int col = lane & 31, khalf = lane >> 5;
  const int h0 = blockIdx.x*4, d0 = blockIdx.y*4, b = blockIdx.z;
  const bool edge = (d0==0) || (d0==DD_-4) || (h0==0) || (h0==HH_-4);

  if (tid < 72){
    int row = tid >> 1, slot = tid & 1;
    *(uint4*)(xs + row*1056 + slot*1040) = make_uint4(0,0,0,0);
  }
  if (edge){
    #pragma unroll 1
    for (int row=0; row<36; ++row){
      int d_ = d0-1+row/6, h_ = h0-1+row-6*(row/6);
      if ((unsigned)d_ < 64u && (unsigned)h_ < 64u) continue;
      if (tid < 64){
        *(uint4*)(xs + row*1056 + (tid+1)*16) = make_uint4(0,0,0,0);
      }
    }
  }

  int soff[9]; int sdst[9]; unsigned svalid = 0;
  #pragma unroll
  for (int it=0; it<9; ++it){
    int row = it*4 + hl;
    int rd = row/6;
    int d_ = d0 - 1 + rd, h_ = h0 - 1 + row - 6*rd;
    bool v = !edge || ((unsigned)d_ < 64u && (unsigned)h_ < 64u);
    if (v) svalid |= (1u<<it);
    int dc = v ? d_ : 0, hc = v ? h_ : 0;
    soff[it] = (dc*4096 + hc*64 + lane)*16;
    sdst[it] = row*1056 + 16;
  }

  // 6 accumulator chains: [kh][whalf]
  floatx16 accA0 = (floatx16)(0.f), accA1 = (floatx16)(0.f), accA2 = (floatx16)(0.f);
  floatx16 accB0 = (floatx16)(0.f), accB1 = (floatx16)(0.f), accB2 = (floatx16)(0.f);

  const long* wAv = (const long*)wA;
  const int bpoff = hl*1056 + col*16 + khalf*8;

#define STAGE(ccv) { \
  const unsigned char* plane = featT + (size_t)(b*4+(ccv))*LL*16; \
  _Pragma("unroll") \
  for (int it=0; it<9; ++it){ \
    if (svalid & (1u<<it)){ \
      __builtin_amdgcn_global_load_lds( \
        (const __attribute__((address_space(1))) void*)(plane + soff[it]), \
        (__attribute__((address_space(3))) void*)(xs + sdst[it]), 16, 0, 0); \
    } \
  } }

#define LOADA(dst, ccv, rrv) { \
  _Pragma("unroll") \
  for (int q=0;q<9;++q) dst[q] = wAv[(size_t)(((rrv)*9+q)*4+(ccv))*64 + lane]; }

#define KHW(areg, rrv, khv, aA, aB) \
  if ((unsigned)(h0+hl-1+(khv)) < 64u){ \
    const unsigned char* bp = xs + bpoff + (rrv)*6336 + (khv)*1056; \
    _Pragma("unroll") \
    for (int kw=0;kw<3;++kw){ \
      long a = areg[(khv)*3+kw]; \
      long b0 = *(const long*)(bp + kw*16); \
      aA = __builtin_amdgcn_mfma_f32_32x32x16_fp8_fp8(a, b0, aA, 0,0,0); \
      long b1 = *(const long*)(bp + kw*16 + 512); \
      aB = __builtin_amdgcn_mfma_f32_32x32x16_fp8_fp8(a, b1, aB, 0,0,0); \
    } }

#define COMPR(areg, rrv) \
  if ((unsigned)(d0-1+(rrv)) < 64u){ \
    KHW(areg, rrv, 0, accA0, accB0) \
    KHW(areg, rrv, 1, accA1, accB1) \
    KHW(areg, rrv, 2, accA2, accB2) \
  }

  long aP[9], aQ[9];
  LOADA(aP, 0, 0);

  #pragma unroll 1
  for (int cc=0; cc<4; ++cc){
    if (cc) __syncthreads();
    STAGE(cc);
    __syncthreads();
    LOADA(aQ, cc, 1);             COMPR(aP, 0);
    LOADA(aP, cc, 2);             COMPR(aQ, 1);
    LOADA(aQ, cc, 3);             COMPR(aP, 2);
    LOADA(aP, cc, 4);             COMPR(aQ, 3);
    LOADA(aQ, cc, 5);             COMPR(aP, 4);
    { int nc = (cc+1)&3; LOADA(aP, nc, 0); }  COMPR(aQ, 5);
  }

  floatx16 accA = accA0 + accA1 + accA2;
  floatx16 accB = accB0 + accB1 + accB2;

  float bg = 0.f, om = 0.f;
  const int h = h0 + hl;
  #pragma unroll
  for (int wh=0; wh<2; ++wh){
    const int w = wh*32 + col;
    #pragma unroll
    for (int dq=0; dq<4; ++dq){
      int d = d0 + dq;
      size_t l = (size_t)d*4096 + (size_t)h*64 + w;
      float v0 = wh ? accB[dq*4+0] : accA[dq*4+0];
      float v1 = wh ? accB[dq*4+1] : accA[dq*4+1];
      float v2 = wh ? accB[dq*4+2] : accA[dq*4+2];
      float v3 = wh ? accB[dq*4+3] : accA[dq*4+3];
      if (khalf == 0){
        float z0 = v0 + cls_b[0]; logits_ws[(size_t)(b*NCLS+0)*LL + l] = z0;
        float z1 = v1 + cls_b[1]; logits_ws[(size_t)(b*NCLS+1)*LL + l] = z1;
        float z2 = v2 + cls_b[2]; logits_ws[(size_t)(b*NCLS+2)*LL + l] = z2;
        float z3 = v3 + cls_b[3]; logits_ws[(size_t)(b*NCLS+3)*LL + l] = z3;
        float p;
        p = sigmoidf_(z0); bg += 0.75f*p*p*softplusf_(z0);
        p = sigmoidf_(z1); bg += 0.75f*p*p*softplusf_(z1);
        p = sigmoidf_(z2); bg += 0.75f*p*p*softplusf_(z2);
        p = sigmoidf_(z3); bg += 0.75f*p*p*softplusf_(z3);
      } else {
        float z4 = v0 + cls_b[4]; logits_ws[(size_t)(b*NCLS+4)*LL + l] = z4;
        float p = sigmoidf_(z4); bg += 0.75f*p*p*softplusf_(z4);
        float o0 = v1 + off_b[0];
        float o1 = v2 + off_b[1];
        float o2 = v3 + off_b[2];
        om = fmaxf(om, fmaxf(fabsf(o0), fmaxf(fabsf(o1), fabsf(o2))));
        float4 ctr;
        ctr.x = ((float)d+0.5f)*2.f + o0;
        ctr.y = ((float)h+0.5f)*2.f + o1;
        ctr.z = ((float)w+0.5f)*2.f + o2;
        ctr.w = 0.f;
        *(float4*)(centers_ws + ((size_t)b*LL + l)*4) = ctr;
      }
    }
  }
  #pragma unroll
  for (int off=32;off;off>>=1){
    bg += __shfl_down(bg, off);
    om = fmaxf(om, __shfl_xor(om, off));
  }
  if (lane == 0){
    bsum[hl] = bg;
    atomicMax(moff_u, __float_as_uint(om));
  }
  __syncthreads();
  if (tid == 0)
    atomicAdd(bg_sum, bsum[0]+bsum[1]+bsum[2]+bsum[3]);
}

// ---------------- Phase B: bounding-box top-13, NSLAB slabs per (b,n). Grid (64, NSLAB).
__global__ __launch_bounds__(256) void topk_box_kernel(
    const float* __restrict__ logits_ws, const float* __restrict__ centers_ws,
    const float* __restrict__ labels,
    const unsigned* __restrict__ moff_u,
    float* __restrict__ pv, int* __restrict__ pi)   // [64][NSLAB][13]
{
  const int bn = blockIdx.x;
  const int slab = blockIdx.y;
  const int b = bn >> 5, n = bn & 31;
  const int tid = threadIdx.x;

  const float* lb = labels + (b*NMAXG + n)*5;
  const float tx = lb[0], ty = lb[1], tz = lb[2];
  const float cf = lb[3];
  const float sg = lb[4];
  const int lab = (cf == -100.f) ? 0 : (int)cf;
  const float m6 = -3.f/(sg*sg);
  const float moff = __uint_as_float(*moff_u);
  const float R = 2.6336f*sg + moff + 0.05f;

  int i0d = (int)ceilf((tx - R - 1.f)*0.5f); if (i0d < 0) i0d = 0;
  int i1d = (int)floorf((tx + R - 1.f)*0.5f); if (i1d > 63) i1d = 63;
  int i0h = (int)ceilf((ty - R - 1.f)*0.5f); if (i0h < 0) i0h = 0;
  int i1h = (int)floorf((ty + R - 1.f)*0.5f); if (i1h > 63) i1h = 63;
  int i0w = (int)ceilf((tz - R - 1.f)*0.5f); if (i0w < 0) i0w = 0;
  int i1w = (int)floorf((tz + R - 1.f)*0.5f); if (i1w > 63) i1w = 63;
  int nd = i1d-i0d+1, nh = i1h-i0h+1, nw = i1w-i0w+1;
  int total = (nd>0 && nh>0 && nw>0) ? nd*nh*nw : 0;
  int lo = (total*slab)/NSLAB, hi = (total*(slab+1))/NSLAB;

  const float* lg = logits_ws + (size_t)(b*NCLS + lab)*LL;
  const float* cb = centers_ws + (size_t)b*LL*4;

  float v[13]; int ix[13];
  #pragma unroll
  for (int j=0;j<13;++j){ v[j]=-1.f; ix[j]=0x7fffffff; }

  for (int idx = lo + tid; idx < hi; idx += 256){
    int r = idx;
    int wi = r % nw; r /= nw;
    int hi2 = r % nh; int di = r / nh;
    int l = (i0d+di)*4096 + (i0h+hi2)*64 + (i0w+wi);
    float4 c4 = *(const float4*)(cb + (size_t)l*4);
    float dx = c4.x-tx, dy = c4.y-ty, dz = c4.z-tz;
    float e = m6*(dx*dx + dy*dy + dz*dz);
    if (e < -20.8f) continue;
    float a = sigmoidf_(lg[l]) * expf(e);
    if (a > v[12]){
      float cv = a; int ci = l;
      #pragma unroll
      for (int j=0;j<13;++j){
        bool take = (cv > v[j]) || (cv == v[j] && ci < ix[j]);
        float nv = take ? cv : v[j];  float ov = take ? v[j] : cv;
        int   ni = take ? ci : ix[j]; int   oi = take ? ix[j] : ci;
        v[j]=nv; ix[j]=ni; cv=ov; ci=oi;
      }
    }
  }

  const int lane = tid & 63, wvi = tid >> 6;
  float mv = -2.f; int mi = 0x7fffffff;
  #pragma unroll 1
  for (int k=0;k<13;++k){
    float bv = v[0]; int bi = ix[0]; int bl = lane;
    #pragma unroll
    for (int off=32; off; off>>=1){
      float ov2 = __shfl_xor(bv, off);
      int oi = __shfl_xor(bi, off);
      int ol = __shfl_xor(bl, off);
      if (ov2 > bv || (ov2 == bv && oi < bi)){ bv=ov2; bi=oi; bl=ol; }
    }
    if (lane == k){ mv = bv; mi = bi; }
    if (lane == bl){
      #pragma unroll
      for (int j=0;j<12;++j){ v[j]=v[j+1]; ix[j]=ix[j+1]; }
      v[12] = -2.f; ix[12] = 0x7fffffff;
    }
  }
  __shared__ float sv2[4*13]; __shared__ int si2[4*13];
  if (lane < 13){ sv2[wvi*13+lane] = mv; si2[wvi*13+lane] = mi; }
  __syncthreads();
  if (wvi == 0){
    float v2 = -2.f; int i2 = 0x7fffffff;
    if (lane < 52){ v2 = sv2[lane]; i2 = si2[lane]; }
    #pragma unroll 1
    for (int k=0;k<13;++k){
      float bv = v2; int bi = i2; int bl = lane;
      #pragma unroll
      for (int off=32; off; off>>=1){
        float ov2 = __shfl_xor(bv, off);
        int oi = __shfl_xor(bi, off);
        int ol = __shfl_xor(bl, off);
        if (ov2 > bv || (ov2 == bv && oi < bi)){ bv=ov2; bi=oi; bl=ol; }
      }
      if (lane == 0){
        pv[(bn*NSLAB+slab)*TOPKK + k] = bv;
        pi[(bn*NSLAB+slab)*TOPKK + k] = bi;
      }
      if (lane == bl) v2 = -2.f;
    }
  }
}

// ---------------- Phase B2: merge NSLAB partials -> top-13 per (b,n). 64 blocks x 64 thr.
__global__ __launch_bounds__(64) void topk_merge_kernel(
    const float* __restrict__ pv, const int* __restrict__ pi,
    float* __restrict__ tv, int* __restrict__ ti)
{
  const int bn = blockIdx.x;
  const int t = threadIdx.x;       // 64
  const int NC = NSLAB*TOPKK;      // 52
  float v = -2.f; int ix = 0x7fffffff;
  if (t < NC){ v = pv[bn*NC + t]; ix = pi[bn*NC + t]; }
  #pragma unroll 1
  for (int k=0;k<13;++k){
    float bv = v; int bi = ix; int bl = t;
    #pragma unroll
    for (int off=32; off; off>>=1){
      float ov = __shfl_xor(bv, off);
      int oi = __shfl_xor(bi, off);
      int ol = __shfl_xor(bl, off);
      if (ov > bv || (ov == bv && oi < bi)){ bv=ov; bi=oi; bl=ol; }
    }
    if (t==0){ tv[bn*TOPKK+k]=bv; ti[bn*TOPKK+k]=bi; }
    if (t==bl) v = -2.f;
  }
}

// ---------------- Phase C: both batches in one 1024-thread pass, LDS hash table
__global__ __launch_bounds__(1024) void finalize_kernel(
    const float* __restrict__ logits_ws, const float* __restrict__ centers_ws,
    const float* __restrict__ labels,
    const float* __restrict__ tv, const int* __restrict__ ti,
    const float* __restrict__ bg_sum, float* __restrict__ out)
{
  const int tid = threadIdx.x;   // 1024
  __shared__ float gx[64], gy[64], gz[64], gs[64];
  __shared__ int glab[64], gvalid[64];
  __shared__ int hkey[2048], hcnt[2048], hmin[2048];
  __shared__ unsigned maxA[64], maxI[64];
  __shared__ float accD, accC;
  if (tid==0){ accD=0.f; accC=0.f; }
  for (int i=tid;i<2048;i+=1024){ hkey[i]=-1; hcnt[i]=0; hmin[i]=0x7fffffff; }
  if (tid<64){
    const float* lb = labels + tid*5;   // tid = b*32+n
    gx[tid]=lb[0]; gy[tid]=lb[1]; gz[tid]=lb[2];
    float cf = lb[3]; gs[tid]=lb[4];
    int val = (cf != -100.f);
    gvalid[tid]=val; glab[tid]= val ? (int)cf : 0;
    maxA[tid]=0u; maxI[tid]=0u;
  }
  __syncthreads();

  const int e = tid;
  bool ok = false; int l = -1; int n = 0; int b = 0;
  if (e < 2*416){
    b = (e >= 416) ? 1 : 0;
    int eb = e - 416*b;
    n = eb/13; int k = eb - 13*n;
    float v = tv[(b*NMAXG+n)*TOPKK + k];
    l = ti[(b*NMAXG+n)*TOPKK + k];
    ok = gvalid[b*32+n] && (v > 1e-9f);
  }
  int slot = -1;
  if (ok){
    unsigned h = (((unsigned)l * 2654435761u) >> 20) & 1023u;
    for (;;){
      int prev = atomicCAS(&hkey[b*1024 + h], -1, l);
      if (prev == -1 || prev == l){ slot = b*1024 + (int)h; break; }
      h = (h+1) & 1023u;
    }
    atomicAdd(&hcnt[slot], 1);
    atomicMin(&hmin[slot], e);
  }
  __syncthreads();

  bool first = ok && (hmin[slot] == e);
  float a=0.f, iou=0.f; int nstar=0;
  if (first){
    float px = centers_ws[((size_t)b*LL + l)*4 + 0];
    float py = centers_ws[((size_t)b*LL + l)*4 + 1];
    float pz = centers_ws[((size_t)b*LL + l)*4 + 2];
    if (hcnt[slot] == 1){
      nstar = n;
    } else {
      float best = -1.f; int bidx = 0;
      #pragma unroll 1
      for (int nn=0;nn<32;++nn){
        float dx=gx[b*32+nn]-px, dy=gy[b*32+nn]-py, dz=gz[b*32+nn]-pz;
        float d2 = dx*dx+dy*dy+dz*dz;
        float io = expf(-d2/(2.f*gs[b*32+nn]*gs[b*32+nn]));
        if (io > best){ best=io; bidx=nn; }
      }
      nstar = bidx;
    }
    int gi = b*32 + nstar;
    float dx=gx[gi]-px, dy=gy[gi]-py, dz=gz[gi]-pz;
    float d2 = dx*dx+dy*dy+dz*dz;
    float sgv = gs[gi];
    iou = expf(-d2/(2.f*sgv*sgv));
    float z = logits_ws[(size_t)(b*NCLS + glab[gi])*LL + l];
    a = sigmoidf_(z) * expf(-3.f*d2/(sgv*sgv));
    atomicMax(&maxA[gi], __float_as_uint(a));
    atomicMax(&maxI[gi], __float_as_uint(iou));
  }
  __syncthreads();

  if (first){
    int gi = b*32 + nstar;
    float mA = __uint_as_float(maxA[gi]);
    float mI = __uint_as_float(maxI[gi]);
    float score = a*mI/(mA + 1e-9f);
    float z = logits_ws[(size_t)(b*NCLS + glab[gi])*LL + l];
    float p = sigmoidf_(z);
    float t2 = log1pf(expf(-fabsf(z)));
    float spz = fmaxf(z,0.f) + t2;
    float spm = fmaxf(-z,0.f) + t2;
    float corr = score*(score*spm + (1.f-score)*spz) - 0.75f*p*p*spz;
    float reg  = (1.f - iou)*score;
    atomicAdd(&accD, score);
    atomicAdd(&accC, corr + reg);
  }
  __syncthreads();
  if (tid==0) out[0] = (bg_sum[0] + accC) / accD;
}

extern "C" void kernel_launch(void* const* d_in, const int* in_sizes, int n_in,
                              void* d_out, int out_size, void* d_ws, size_t ws_size,
                              hipStream_t stream) {
  const float* feat  = (const float*)d_in[0];
  const float* cls_w = (const float*)d_in[1];
  const float* cls_b = (const float*)d_in[2];
  const float* off_w = (const float*)d_in[3];
  const float* off_b = (const float*)d_in[4];
  const float* labels= (const float*)d_in[5];
  float* out = (float*)d_out;

  float* logits_ws  = (float*)d_ws;                              // 2*5*L f32
  float* centers_ws = logits_ws + (size_t)NB*NCLS*LL;            // 2*L*4 f32
  float* tv = centers_ws + (size_t)NB*LL*4;                      // 64*13
  int*   ti = (int*)(tv + 64*TOPKK);
  float* pv = (float*)(ti + 64*TOPKK);                           // 64*NSLAB*13
  int*   pi = (int*)(pv + 64*NSLAB*TOPKK);
  float* bg = (float*)(pi + 64*NSLAB*TOPKK);                     // [0]=bg,[1]=moff
  unsigned char* wA = (unsigned char*)(bg + 16);                 // 216*64*8 fp8 bytes
  unsigned char* featT = wA + 216*64*8;                          // 33.5MB

  transpose_kernel<<<dim3(64,16,2), 256, 0, stream>>>(
      feat, featT, cls_w, off_w, wA, bg);
  conv_mfma_kernel<<<dim3(16,16,2), 256, 0, stream>>>(
      featT, wA, cls_b, off_b, logits_ws, centers_ws, bg, (unsigned*)(bg+1));
  topk_box_kernel<<<dim3(64,NSLAB), 256, 0, stream>>>(
      logits_ws, centers_ws, labels, (const unsigned*)(bg+1), pv, pi);
  topk_merge_kernel<<<64, 64, 0, stream>>>(pv, pi, tv, ti);
  finalize_kernel<<<1, 1024, 0, stream>>>(
      logits_ws, centers_ws, labels, tv, ti, bg, out);
}